// Round 1
// baseline (93.791 us; speedup 1.0000x reference)
//
#include <hip/hip_runtime.h>
#include <math.h>

#define N_BOX 256
#define M_PTS 512
#define SPLIT 2   // blocks per box: each handles 256 of the 512 m1 rows

// block = 256 threads; grid = N_BOX*SPLIT = 512 blocks -> 2 blocks/CU, 2 waves/SIMD
__global__ __launch_bounds__(256, 2) void loss_kernel(
    const float* __restrict__ pred,    // (N,5)
    const float* __restrict__ target,  // (N,5)
    const float* __restrict__ mask,    // (N,M,2)
    const float* __restrict__ gradx,   // (N,M)
    const float* __restrict__ grady,   // (N,M)
    const float* __restrict__ offset,  // (N,2)
    float* __restrict__ out)           // scalar accumulator (pre-zeroed)
{
    __shared__ float4 sPack[M_PTS];    // {mx, my, gradx*a1/(2*pi*theta), grady*a1/(2*pi*theta)}
    __shared__ float  sWave[4];

    const int n    = blockIdx.x & (N_BOX - 1);
    const int half = blockIdx.x >> 8;         // 0 or 1: which m1 half this block owns
    const int t    = threadIdx.x;

    const float offx = offset[n * 2 + 0];
    const float offy = offset[n * 2 + 1];
    const float px = pred[n * 5 + 0] - offx;
    const float py = pred[n * 5 + 1] - offy;
    const float pw = pred[n * 5 + 2];
    const float ph = pred[n * 5 + 3];
    const float pa = pred[n * 5 + 4];
    const float gx = target[n * 5 + 0] - offx;
    const float gy = target[n * 5 + 1] - offy;
    const float gw = target[n * 5 + 2];
    const float gh = target[n * 5 + 3];
    const float ga = target[n * 5 + 4];

    float sinpa, cospa;
    sincosf(pa, &sinpa, &cospa);

    const float KC       = 15.0f;
    const float THETA2   = 400.0f;
    const float inv_norm = 1.0f / (2.0f * (float)M_PI * THETA2);
    const float PI  = (float)M_PI;
    const float HPI = (float)M_PI * 0.5f;

    // ---- phase 1: per-m geometry (each thread does m = t and m = t+256) ----
    float G1x = 0.0f, G1y = 0.0f, g1x = 0.0f, g1y = 0.0f;
#pragma unroll
    for (int j = 0; j < 2; ++j) {
        const int m = t + j * 256;
        const float mx = mask[((size_t)n * M_PTS + m) * 2 + 0];
        const float my = mask[((size_t)n * M_PTS + m) * 2 + 1];
        const float dx = mx - gx;
        const float dy = my - gy;
        const float d  = sqrtf(dx * dx + dy * dy);
        float aa = (gx - mx) / d;
        aa = fminf(1.0f, fmaxf(-1.0f, aa));
        const float ac   = acosf(aa);
        const float beta = (gy >= my) ? (ga + ac) : (ga - ac);
        float sb, cb;
        sincosf(beta, &sb, &cb);
        const float d_w = fabsf(d * cb);
        const float d_h = fabsf(d * sb);
        const float s1  = 1.0f / (1.0f + expf(-(KC * (d_w - gw) / gw)));
        const float s2  = 1.0f / (1.0f + expf(-(KC * (d_h - gh) / gh)));
        const float a1  = (1.0f - s1) * (1.0f - s2);
        const float dwp = pw * d_w / gw;
        const float dhp = ph * d_h / gh;
        const float wx = dwp * cospa, wy = dwp * sinpa;
        const float hx = -dhp * sinpa, hy = dhp * cospa;
        // quadrant corner select (priority-ordered as in reference)
        float gpx, gpy;
        if (beta > -HPI && beta <= 0.0f)        { gpx =  wx - hx; gpy =  wy - hy; }
        else if (beta > -PI && beta <= -HPI)    { gpx =  wx + hx; gpy =  wy + hy; }
        else if (beta >  HPI && beta <=  PI)    { gpx = -wx + hx; gpy = -wy + hy; }
        else                                    { gpx = -wx - hx; gpy = -wy - hy; }
        const float gX  = px + gpx;
        const float gY  = py + gpy;
        const float gvx = gradx[(size_t)n * M_PTS + m];
        const float gvy = grady[(size_t)n * M_PTS + m];
        const float B   = a1 * inv_norm;
        sPack[m] = make_float4(mx, my, gvx * B, gvy * B);
        if (j == half) { G1x = gX; G1y = gY; g1x = gvx; g1y = gvy; }
    }
    __syncthreads();

    // ---- phase 2: inner M loop; wave-uniform LDS broadcast reads ----
    // exp(s / (2*theta^2)) -> exp2(s * log2e / (2*theta^2))
    const float c1 = 1.4426950408889634f / (2.0f * THETA2 * THETA2);
    float acc = 0.0f;
#pragma unroll 8
    for (int m2 = 0; m2 < M_PTS; ++m2) {
        const float4 p = sPack[m2];
        const float dgx = G1x - p.x;
        const float dgy = G1y - p.y;
        const float s   = fmaf(dgy, dgy, dgx * dgx);
        const float e   = exp2f(s * c1);
        const float w   = fmaf(g1y, p.w, g1x * p.z);
        acc = fmaf(w, e, acc);
    }

    // ---- reduce: wave shuffle -> LDS -> one atomic per block ----
#pragma unroll
    for (int off = 32; off > 0; off >>= 1)
        acc += __shfl_down(acc, off, 64);
    if ((t & 63) == 0) sWave[t >> 6] = acc;
    __syncthreads();
    if (t == 0) {
        const float tot = sWave[0] + sWave[1] + sWave[2] + sWave[3];
        const float scale = 1.0f / ((float)N_BOX * (float)M_PTS * (float)M_PTS);
        atomicAdd(out, tot * scale);
    }
}

extern "C" void kernel_launch(void* const* d_in, const int* in_sizes, int n_in,
                              void* d_out, int out_size, void* d_ws, size_t ws_size,
                              hipStream_t stream) {
    const float* pred   = (const float*)d_in[0];
    const float* target = (const float*)d_in[1];
    const float* mask   = (const float*)d_in[2];
    const float* gradx  = (const float*)d_in[3];
    const float* grady  = (const float*)d_in[4];
    const float* offset = (const float*)d_in[5];
    float* out = (float*)d_out;

    hipMemsetAsync(out, 0, sizeof(float), stream);
    hipLaunchKernelGGL(loss_kernel, dim3(N_BOX * SPLIT), dim3(256), 0, stream,
                       pred, target, mask, gradx, grady, offset, out);
}

// Round 2
// 81.228 us; speedup vs baseline: 1.1547x; 1.1547x over previous
//
#include <hip/hip_runtime.h>
#include <math.h>

typedef float v2f __attribute__((ext_vector_type(2)));

#define N_BOX   256
#define M_PTS   512
#define S_SPLIT 8                    // m2-range splits per box
#define BLK     64                   // 1 wave per block
#define R_ROWS  8                    // m1 rows per thread (BLK*R_ROWS = M_PTS)
#define M2_PER  (M_PTS / S_SPLIT)    // 64 m2 per block
#define GRID    (N_BOX * S_SPLIT)    // 2048 blocks

// Each block: box n = blockIdx>>3, m2 slice s = blockIdx&7.
// Thread t owns m1 rows {t + 64*r, r=0..7}; one ds_read_b128 per m2 feeds 8 rows.
__global__ __launch_bounds__(BLK, 2) void loss_main(
    const float* __restrict__ pred,    // (N,5)
    const float* __restrict__ target,  // (N,5)
    const float* __restrict__ mask,    // (N,M,2)
    const float* __restrict__ gradx,   // (N,M)
    const float* __restrict__ grady,   // (N,M)
    const float* __restrict__ offset,  // (N,2)
    float* __restrict__ part)          // (GRID,) partial sums
{
    __shared__ float4 sPack[M2_PER];   // {mx*rs, my*rs, gvx*B, gvy*B} for this m2 slice

    const int n = blockIdx.x >> 3;
    const int s = blockIdx.x & 7;
    const int t = threadIdx.x;

    const float offx = offset[n * 2 + 0];
    const float offy = offset[n * 2 + 1];
    const float px = pred[n * 5 + 0] - offx;
    const float py = pred[n * 5 + 1] - offy;
    const float pw = pred[n * 5 + 2];
    const float ph = pred[n * 5 + 3];
    const float pa = pred[n * 5 + 4];
    const float gx = target[n * 5 + 0] - offx;
    const float gy = target[n * 5 + 1] - offy;
    const float gw = target[n * 5 + 2];
    const float gh = target[n * 5 + 3];
    const float ga = target[n * 5 + 4];

    float sinpa, cospa, singa, cosga;
    sincosf(pa, &sinpa, &cospa);
    sincosf(ga, &singa, &cosga);

    const float THETA2   = 400.0f;
    const float LOG2E    = 1.4426950408889634f;
    const float c1       = LOG2E / (2.0f * THETA2 * THETA2);  // exp2 scale on dist^2
    const float rs       = sqrtf(c1);                          // fold into coordinates
    const float inv_norm = 1.0f / (2.0f * (float)M_PI * THETA2);

    // per-box folded constants
    const float pwg = pw / gw, phg = ph / gh;
    const float cwx = pwg * cospa, swx = pwg * sinpa;   // wx = dws*cwx etc.
    const float chx = phg * cospa, shx = phg * sinpa;
    const float absinga = fabsf(singa);
    const float kA  = 15.0f * LOG2E / gw;               // sigmoid exponent slopes
    const float kH  = 15.0f * LOG2E / gh;
    const float kB  = 15.0f * LOG2E;
    const float pxrs = px * rs, pyrs = py * rs;
    const bool  gaPos = (ga > 0.0f), gaNeg = (ga < 0.0f);

    const float2* mask2 = (const float2*)mask;
    const size_t  baseM = (size_t)n * M_PTS;

    v2f Gx[4], Gy[4], gvx2[4], gvy2[4];

    // ---- phase 1: per-row geometry, no acos/sincos (rotation identity) ----
#pragma unroll
    for (int r = 0; r < R_ROWS; ++r) {
        const int    m  = t + (r << 6);
        const float2 mp = mask2[baseM + m];
        const float dx = mp.x - gx;
        const float dy = mp.y - gy;
        // u = d*cos(beta), v = d*sin(beta)  (sigma*|dy| == -dy identically)
        const float u = singa * dy - cosga * dx;
        const float v = -(cosga * dy + singa * dx);
        // wrap <=> |beta| > pi  <=> sigma*ga>0 && dx>0 && dx*|sin ga| > |dy|*cos ga
        const bool sgaOk = gaPos ? (dy <= 0.0f) : (gaNeg ? (dy > 0.0f) : false);
        const bool wrap  = sgaOk && (dx > 0.0f) && (dx * absinga > fabsf(dy) * cosga);
        const float au = fabsf(u), av = fabsf(v);     // d_w, d_h
        // corner-select signs: (wrap||v>0) -> -w side ; (wrap||u>0) -> -h side
        const float dws = (wrap || v > 0.0f) ? -au : au;
        const float dhs = (wrap || u > 0.0f) ? -av : av;
        const float gpx = dws * cwx - dhs * shx;
        const float gpy = dws * swx + dhs * chx;
        const float gvx = gradx[baseM + m];
        const float gvy = grady[baseM + m];
        Gx[r >> 1][r & 1]   = fmaf(gpx, rs, pxrs);    // pre-scaled gaussian center
        Gy[r >> 1][r & 1]   = fmaf(gpy, rs, pyrs);
        gvx2[r >> 1][r & 1] = gvx;
        gvy2[r >> 1][r & 1] = gvy;
        if (r == s) {  // this row's m equals this block's m2 = s*64 + t
            // (1-sig(x))(1-sig(y)) = 1/((1+e^x)(1+e^y))
            const float eA = __builtin_amdgcn_exp2f(fmaf(au, kA, -kB));
            const float eB = __builtin_amdgcn_exp2f(fmaf(av, kH, -kB));
            const float B  = inv_norm / ((1.0f + eA) * (1.0f + eB));
            sPack[t] = make_float4(mp.x * rs, mp.y * rs, gvx * B, gvy * B);
        }
    }
    __syncthreads();

    // ---- phase 2: m2 loop; packed f32 pairs; exp-pipe bound ----
    v2f accz[4], accw[4];
#pragma unroll
    for (int q = 0; q < 4; ++q) { accz[q] = (v2f)0.0f; accw[q] = (v2f)0.0f; }

#pragma unroll 4
    for (int m2 = 0; m2 < M2_PER; ++m2) {
        const float4 p = sPack[m2];
#pragma unroll
        for (int q = 0; q < 4; ++q) {
            v2f dgx = Gx[q] - p.x;
            v2f dgy = Gy[q] - p.y;
            v2f sa  = dgx * dgx + dgy * dgy;          // already scaled by c1
            v2f e;
            e.x = __builtin_amdgcn_exp2f(sa.x);
            e.y = __builtin_amdgcn_exp2f(sa.y);
            accz[q] += e * p.z;                        // sum z*e
            accw[q] += e * p.w;                        // sum w*e
        }
    }

    // w-term factorization: sum w*e = gvx*sum(z*e) + gvy*sum(w*e)
    v2f tot2 = accz[0] * gvx2[0] + accw[0] * gvy2[0];
    tot2 += accz[1] * gvx2[1] + accw[1] * gvy2[1];
    tot2 += accz[2] * gvx2[2] + accw[2] * gvy2[2];
    tot2 += accz[3] * gvx2[3] + accw[3] * gvy2[3];
    float acc = tot2.x + tot2.y;

#pragma unroll
    for (int off = 32; off > 0; off >>= 1)
        acc += __shfl_down(acc, off, 64);
    if (t == 0) part[blockIdx.x] = acc;
}

__global__ __launch_bounds__(256) void loss_reduce(const float* __restrict__ part,
                                                   float* __restrict__ out)
{
    __shared__ float sW[4];
    const int t = threadIdx.x;
    const float4* p4 = (const float4*)part;            // 2048 floats = 512 float4
    const float4 a = p4[t];
    const float4 b = p4[t + 256];
    float acc = ((a.x + a.y) + (a.z + a.w)) + ((b.x + b.y) + (b.z + b.w));
#pragma unroll
    for (int off = 32; off > 0; off >>= 1)
        acc += __shfl_down(acc, off, 64);
    if ((t & 63) == 0) sW[t >> 6] = acc;
    __syncthreads();
    if (t == 0) {
        const float scale = 1.0f / ((float)N_BOX * (float)M_PTS * (float)M_PTS);
        out[0] = (sW[0] + sW[1] + sW[2] + sW[3]) * scale;
    }
}

extern "C" void kernel_launch(void* const* d_in, const int* in_sizes, int n_in,
                              void* d_out, int out_size, void* d_ws, size_t ws_size,
                              hipStream_t stream) {
    const float* pred   = (const float*)d_in[0];
    const float* target = (const float*)d_in[1];
    const float* mask   = (const float*)d_in[2];
    const float* gradx  = (const float*)d_in[3];
    const float* grady  = (const float*)d_in[4];
    const float* offset = (const float*)d_in[5];
    float* out  = (float*)d_out;
    float* part = (float*)d_ws;   // 2048 floats of scratch

    hipLaunchKernelGGL(loss_main, dim3(GRID), dim3(BLK), 0, stream,
                       pred, target, mask, gradx, grady, offset, part);
    hipLaunchKernelGGL(loss_reduce, dim3(1), dim3(256), 0, stream, part, out);
}